// Round 1
// baseline (628.891 us; speedup 1.0000x reference)
//
#include <hip/hip_runtime.h>
#include <math.h>

#define NWAY 5
#define NSUP 25
#define NZV  125
#define DF   640
#define NQ   75
#define TPB  320   // ONE batch per block, 5 waves; grid = B (=512) -> 2 independent blocks/CU

// =====================================================================
// Fast transform: tf(x) = sign(x) * (g(|x|+1e-5) - g(1e-5)),
//   g(t) = ln(1/t+1)^{-1.3} = exp2(-1.3*log2(log2(1/t+1)) + A),
//   A = -1.3*log2(ln2) = 0.68739628. 4 transcendentals vs reference's 8.
// =====================================================================
__device__ __forceinline__ float gfun(float t) {
  const float l2 = __log2f(__builtin_amdgcn_rcpf(t) + 1.0f);
  return __builtin_amdgcn_exp2f(fmaf(-1.3f, __log2f(l2), 0.68739628f));
}
__device__ __forceinline__ float simple_tf(float x, float Cg) {
  const float s = gfun(fabsf(x) + 1e-5f) - Cg;
  return (x >= 0.0f) ? s : -s;
}

// Constant-lane fp64 broadcast via v_readlane (VALU, off the LDS pipe).
__device__ __forceinline__ double bcastd(double v, const int srclane) {
  const int lo = __builtin_amdgcn_readlane(__double2loint(v), srclane);
  const int hi = __builtin_amdgcn_readlane(__double2hiint(v), srclane);
  return __hiloint2double(hi, lo);
}

// In-place Gauss-Jordan of 25x25 SPD; columns live on lanes BASE..BASE+24.
template <int BASE, int J>
__device__ __forceinline__ void gjp(double (&a)[25], const int lane,
                                    const bool act) {
  const double djj = bcastd(a[J], BASE + J);
  const double pinv = 1.0 / djj;
  if (act) a[J] = ((lane == BASE + J) ? 1.0 : a[J]) * pinv;
#pragma unroll
  for (int r = 0; r < 25; ++r) {
    if (r != J) {
      const double f = bcastd(a[r], BASE + J);
      if (act) a[r] = ((lane == BASE + J) ? 0.0 : a[r]) - f * a[J];
    }
  }
}
template <int BASE, int J = 0>
__device__ __forceinline__ void gjall(double (&a)[25], const int lane,
                                      const bool act) {
  if constexpr (J < 25) {
    gjp<BASE, J>(a, lane, act);
    gjall<BASE, J + 1>(a, lane, act);
  }
}

// Factorize: hv <- row `lane` of Hinv_w; wave-0 lanes 32-56 additionally
// get Winv = (sum_k Hinv_k)^-1 rows.
__device__ __forceinline__ void factorize(const double* Msh, const double* dd,
                                          double* W, double (&hv)[25],
                                          const int tl, const int lane,
                                          const int w) {
  if (lane < 25) {
#pragma unroll
    for (int j = 0; j < 25; ++j)
      hv[j] = Msh[lane * 26 + j] + ((j == lane) ? dd[lane * 5 + w] : 0.0);
  }
  gjall<0>(hv, lane, true);
  for (int i2 = tl; i2 < 650; i2 += 320) W[i2] = 0.0;
  __syncthreads();
#pragma unroll
  for (int k = 0; k < 5; ++k) {
    if (w == k && lane < 25) {
#pragma unroll
      for (int j = 0; j < 25; ++j) W[lane * 26 + j] += hv[j];
    }
    __syncthreads();
  }
  if (w == 0) {
    if (lane >= 32 && lane < 57) {
#pragma unroll
      for (int r = 0; r < 25; ++r) hv[r] = W[(lane - 32) * 26 + r];
    }
    gjall<32>(hv, lane, lane >= 32 && lane < 57);
  }
  // next consumer phase begins with its own __syncthreads()
}

// KKT solve. ZRS: rs==0; ZR: rx=rz=ry==0; ACC: accumulate.
// dyw: scratch for THIS solve's dy (back-substitution uses it, not the
// accumulated dy).
template <bool ZRS, bool ZR, bool ACC>
__device__ __forceinline__ void kkt_solve(
    const double* Msh, const double* dd, double* tt, double* c1, double* c2,
    double* vv, double* gg, double* dyw, const double* rx, const double* rs,
    const double* rz, const double* ry, double (&hv)[25], double* dx,
    double* ds, double* dz, double* dy, const int tl, const int lane,
    const int w) {
  if (tl < NZV) {
    double t = ZR ? 0.0 : rz[tl];
    if (!ZRS) t -= rs[tl] / dd[tl];
    tt[tl] = t;
  }
  __syncthreads();
  if (tl < NZV) {
    const int i = tl / 5, k = tl - i * 5;
    double acc = ZR ? 0.0 : -rx[tl];
#pragma unroll
    for (int j = 0; j < 25; ++j) acc += Msh[i * 26 + j] * tt[j * 5 + k];
    c1[tl] = acc;
  } else if (tl >= 128 && tl < 153) {
    const int i = tl - 128;
    double acc = ZR ? 0.0 : -ry[i];
#pragma unroll
    for (int k = 0; k < 5; ++k) acc += tt[i * 5 + k];
    c2[i] = acc;
  }
  __syncthreads();
  if (lane < 25) {
    double acc = 0.0;
#pragma unroll
    for (int j = 0; j < 25; ++j) acc += hv[j] * c1[j * 5 + w];
    vv[lane * 5 + w] = acc;
  }
  __syncthreads();
  if (w == 0) {  // gg then dy in the SAME wave: LDS program order suffices
    if (lane < 25) {
      double acc = -c2[lane];
#pragma unroll
      for (int k = 0; k < 5; ++k) acc += vv[lane * 5 + k];
      gg[lane] = acc;
    }
    if (lane >= 32 && lane < 57) {
      double acc = 0.0;
#pragma unroll
      for (int r = 0; r < 25; ++r) acc += hv[r] * gg[r];
      dyw[lane - 32] = acc;
      if (ACC) dy[lane - 32] += acc; else dy[lane - 32] = acc;
    }
  }
  __syncthreads();
  if (lane < 25) {
    double acc = 0.0;
#pragma unroll
    for (int j = 0; j < 25; ++j) acc += hv[j] * dyw[j];
    const int v = lane * 5 + w;
    const double u = vv[v] - acc;
    const double dzv = dd[v] * u;
    const double dxv = u - tt[v];
    const double dsv = ((ZRS ? 0.0 : -rs[v]) - dzv) / dd[v];
    if (ACC) { dz[v] += dzv; dx[v] += dxv; ds[v] += dsv; }
    else     { dz[v]  = dzv; dx[v]  = dxv; ds[v]  = dsv; }
  }
  __syncthreads();
}

// Block reduction: wave 0 reduces buf[0..n).
__device__ __forceinline__ double bred(const double* buf, int n, int ismin,
                                       double* SCh, const int w,
                                       const int lane) {
  __syncthreads();
  if (w == 0) {
    double acc = ismin ? 1e300 : 0.0;
    for (int m = lane; m < n; m += 64) {
      const double v = buf[m];
      acc = ismin ? fmin(acc, v) : (acc + v);
    }
#pragma unroll
    for (int off = 32; off > 0; off >>= 1) {
      const double o = __shfl_xor(acc, off);
      acc = ismin ? fmin(acc, o) : (acc + o);
    }
    if (lane == 0) SCh[15] = acc;
  }
  __syncthreads();
  return SCh[15];
}

// stage 64 columns of transformed+normalized train rows into GBUF[25][68]
__device__ __forceinline__ void stage_chunk(const float* __restrict__ tb,
                                            const int ch, const bool us,
                                            const float Cg,
                                            const float* invn, float* GBUF,
                                            const int tl) {
  for (int idx = tl; idx < 1600; idx += 320) {
    const int r = idx >> 6, cc = idx & 63;
    float v = tb[r * DF + (ch << 6) + cc];
    if (us) v = simple_tf(v, Cg);
    GBUF[r * 68 + cc] = v * invn[r];
  }
}

// =====================================================================
// fused_kernel: ONE batch per 320-thread block (5 waves), grid = B.
// 2 blocks/CU co-resident with INDEPENDENT barrier schedules (the old
// 2-halves-in-one-block design lock-stepped both batches through every
// __syncthreads). QP result stays in LDS; the query dot-product phase
// (old out_kernel) runs in the same block -> no xfg round-trip, no
// second launch, and the out-phase work fills the other block's
// latency gaps.
// =====================================================================
__global__ void __launch_bounds__(TPB, 2) fused_kernel(
    const float* __restrict__ train, const float* __restrict__ test,
    const int* __restrict__ usimple, float* __restrict__ out) {
  const int tl = threadIdx.x;
  const int lane = tl & 63;
  const int w = tl >> 6;
  const int bb = blockIdx.x;
  const bool us = (usimple[0] != 0);
  const float Cg = gfun(1e-5f);

  __shared__ double Msh[650];
  __shared__ __align__(16) unsigned char GBW[6800];
  __shared__ double x[125], sv[125], zv[125], rx[125], rz[125], dd[125],
      tt[125], c1[125], vv[125], dxa[125], dsa[125], dza[125], rsc[125];
  __shared__ double yv[25], ry[25], c2[25], gg[25], dya[25], dyw[25];
  __shared__ double SC[16];
  __shared__ float invn[25];
  __shared__ float bxs[125];
  __shared__ float xfs[NWAY * DF];

  double* W = (double*)GBW;
  float* GBUF = (float*)GBW;
  double hv[25];

  const float* tb = train + (size_t)bb * NSUP * DF;

  // ---- phase 1: row norms ----
#pragma unroll
  for (int jj = 0; jj < 5; ++jj) {
    const int r = w * 5 + jj;
    float ss = 0.0f;
#pragma unroll
    for (int c = 0; c < 10; ++c) {
      float v = tb[r * DF + lane + 64 * c];
      if (us) v = simple_tf(v, Cg);
      ss += v * v;
    }
#pragma unroll
    for (int off = 32; off > 0; off >>= 1) ss += __shfl_xor(ss, off);
    if (lane == 0) invn[r] = 1.0f / fmaxf(sqrtf(ss), 1e-12f);
  }
  __syncthreads();

  // ---- phase 2: chunked Gram, M = FT FT^T + I (fp64 accumulate) ----
  int i1, j1, i2v = 0, j2v = 0;
  {
    int rem = tl, i = 0;
    while (rem >= NSUP - i) { rem -= NSUP - i; ++i; }
    i1 = i; j1 = i + rem;
  }
  if (tl < 5) {
    int rem = 320 + tl, i = 0;
    while (rem >= NSUP - i) { rem -= NSUP - i; ++i; }
    i2v = i; j2v = i + rem;
  }
  double acc1 = 0.0, acc2 = 0.0;
  for (int ch = 0; ch < 10; ++ch) {
    stage_chunk(tb, ch, us, Cg, invn, GBUF, tl);
    __syncthreads();
    {
      const float4* ra = (const float4*)(GBUF + i1 * 68);
      const float4* rb = (const float4*)(GBUF + j1 * 68);
#pragma unroll
      for (int c = 0; c < 16; ++c) {
        float4 av = ra[c], bv = rb[c];
        acc1 += (double)av.x * bv.x + (double)av.y * bv.y +
                (double)av.z * bv.z + (double)av.w * bv.w;
      }
    }
    if (tl < 5) {
      const float4* ra = (const float4*)(GBUF + i2v * 68);
      const float4* rb = (const float4*)(GBUF + j2v * 68);
#pragma unroll
      for (int c = 0; c < 16; ++c) {
        float4 av = ra[c], bv = rb[c];
        acc2 += (double)av.x * bv.x + (double)av.y * bv.y +
                (double)av.z * bv.z + (double)av.w * bv.w;
      }
    }
    __syncthreads();
  }
  if (i1 == j1) acc1 += 1.0;
  Msh[i1 * 26 + j1] = acc1;
  if (i1 != j1) Msh[j1 * 26 + i1] = acc1;
  if (tl < 5) {
    if (i2v == j2v) acc2 += 1.0;   // pairs 322/324 are diagonal
    Msh[i2v * 26 + j2v] = acc2;
    if (i2v != j2v) Msh[j2v * 26 + i2v] = acc2;
  }

  // ---- phase 3: QP ----
  if (tl < NZV) {
    const int i = tl / 5, k = tl - i * 5;
    const double oh = (k == (i % 5)) ? 1.0 : 0.0;
    rx[tl] = -oh;
    rz[tl] = -0.1 * oh;
    dd[tl] = 1.0;
  } else if (tl >= 128 && tl < 153) {
    ry[tl - 128] = 0.0;
  }
  if (tl == 0) SC[0] = 1e300;
  __syncthreads();

  factorize(Msh, dd, W, hv, tl, lane, w);
  kkt_solve<true, false, false>(Msh, dd, tt, c1, c2, vv, gg, dyw, rx,
                                (const double*)nullptr, rz, ry, hv, x, sv, zv,
                                yv, tl, lane, w);
  {
    const double ms = bred(sv, NZV, 1, SC, w, lane);
    if (ms < 0.0 && tl < NZV) sv[tl] -= (ms - 1.0);
    const double mz = bred(zv, NZV, 1, SC, w, lane);
    if (mz < 0.0 && tl < NZV) zv[tl] -= (mz - 1.0);
  }
  if (tl < NZV) bxs[tl] = (float)x[tl];

#pragma unroll 1
  for (int it = 0; it < 3; ++it) {
    __syncthreads();
    if (tl < NZV) {
      const int i = tl / 5, k = tl - i * 5;
      double acc = 0.0;
#pragma unroll
      for (int j = 0; j < 25; ++j) acc += Msh[i * 26 + j] * x[j * 5 + k];
      const double oh = (k == (i % 5)) ? 1.0 : 0.0;
      rx[tl] = yv[i] + zv[tl] + acc - oh;
      rz[tl] = x[tl] + sv[tl] - 0.1 * oh;
    } else if (tl >= 128 && tl < 153) {
      const int i = tl - 128;
      double acc = 0.0;
#pragma unroll
      for (int k = 0; k < 5; ++k) acc += x[i * 5 + k];
      ry[i] = acc;
    }
    __syncthreads();
    if (w == 0) {  // consolidated 4-sum reduction on wave 0
      double s1 = 0, s2 = 0, s3 = 0, s4 = 0;
      for (int m = lane; m < 125; m += 64) {
        s1 += sv[m] * zv[m];
        s2 += rx[m] * rx[m];
        s3 += rz[m] * rz[m];
      }
      if (lane < 25) s4 = ry[lane] * ry[lane];
#pragma unroll
      for (int off = 32; off > 0; off >>= 1) {
        s1 += __shfl_xor(s1, off);
        s2 += __shfl_xor(s2, off);
        s3 += __shfl_xor(s3, off);
        s4 += __shfl_xor(s4, off);
      }
      if (lane == 0) { SC[2] = s1; SC[3] = s2; SC[4] = s3; SC[5] = s4; }
    }
    __syncthreads();
    const double szsum = SC[2];
    const double mu = fabs(szsum) / 125.0;
    const double res = sqrt(SC[4] + 1e-30) + sqrt(SC[5] + 1e-30) +
                       sqrt(SC[3] + 1e-30) + 125.0 * mu;
    if (tl == 0) {
      if (res < SC[0]) { SC[0] = res; SC[1] = 1.0; } else SC[1] = 0.0;
    }
    __syncthreads();
    if (SC[1] != 0.0 && tl < NZV) bxs[tl] = (float)x[tl];
    if (it == 2) break;
    __syncthreads();

    if (tl < NZV) dd[tl] = zv[tl] / sv[tl];
    __syncthreads();
    factorize(Msh, dd, W, hv, tl, lane, w);
    kkt_solve<false, false, false>(Msh, dd, tt, c1, c2, vv, gg, dyw, rx, zv,
                                   rz, ry, hv, dxa, dsa, dza, dya, tl, lane,
                                   w);
    if (tl < NZV) {
      const double a1 = (dza[tl] < 0.0) ? (-zv[tl] / dza[tl]) : 1e12;
      const double a2 = (dsa[tl] < 0.0) ? (-sv[tl] / dsa[tl]) : 1e12;
      tt[tl] = fmin(a1, a2);
    }
    const double aff = fmin(bred(tt, NZV, 1, SC, w, lane), 1.0);
    if (tl < NZV)
      tt[tl] = (sv[tl] + aff * dsa[tl]) * (zv[tl] + aff * dza[tl]);
    const double num = bred(tt, NZV, 0, SC, w, lane);
    const double sg = num / szsum;
    const double musig = mu * (sg * sg * sg);
    if (tl < NZV) rsc[tl] = (-musig + dsa[tl] * dza[tl]) / sv[tl];
    __syncthreads();
    kkt_solve<false, true, true>(Msh, dd, tt, c1, c2, vv, gg, dyw, rx, rsc,
                                 rz, ry, hv, dxa, dsa, dza, dya, tl, lane,
                                 w);
    if (tl < NZV) {
      const double a1 = (dza[tl] < 0.0) ? (-zv[tl] / dza[tl]) : 1e12;
      const double a2 = (dsa[tl] < 0.0) ? (-sv[tl] / dsa[tl]) : 1e12;
      tt[tl] = fmin(a1, a2);
    }
    const double al = fmin(0.999 * bred(tt, NZV, 1, SC, w, lane), 1.0);
    if (tl < NZV) {
      x[tl] += al * dxa[tl];
      sv[tl] += al * dsa[tl];
      zv[tl] += al * dza[tl];
    } else if (tl >= 128 && tl < 153) {
      const int i = tl - 128;
      yv[i] += al * dya[i];
    }
  }
  __syncthreads();

  // ---- phase 4: xfs[w][d] = sum_s bx[s,w] * FT[s][d], chunked, to LDS ----
  float xs[25];
#pragma unroll
  for (int s_ = 0; s_ < 25; ++s_) xs[s_] = bxs[s_ * 5 + w];
  for (int ch = 0; ch < 10; ++ch) {
    stage_chunk(tb, ch, us, Cg, invn, GBUF, tl);
    __syncthreads();
    float acc = 0.0f;
#pragma unroll
    for (int s_ = 0; s_ < 25; ++s_) acc += xs[s_] * GBUF[s_ * 68 + lane];
    xfs[w * DF + (ch << 6) + lane] = acc;
    __syncthreads();
  }
  // trailing __syncthreads above makes all xfs writes visible

  // ---- phase 5: query dot products (old out_kernel, now fused) ----
  // wave w handles queries w, w+5, ..., w+70 (15 each). unroll 2 keeps
  // two queries' global loads in flight.
  const float* qb = test + (size_t)bb * NQ * DF;
#pragma unroll 2
  for (int jj = 0; jj < 15; ++jj) {
    const int q = w + 5 * jj;
    const float* qr = qb + (size_t)q * DF;
    float nrm = 0.0f, a0 = 0.0f, a1 = 0.0f, a2 = 0.0f, a3 = 0.0f, a4 = 0.0f;
#pragma unroll
    for (int c = 0; c < 10; ++c) {
      const int d = lane + 64 * c;
      float v = qr[d];
      if (us) v = simple_tf(v, Cg);
      nrm += v * v;
      a0 += v * xfs[0 * DF + d];
      a1 += v * xfs[1 * DF + d];
      a2 += v * xfs[2 * DF + d];
      a3 += v * xfs[3 * DF + d];
      a4 += v * xfs[4 * DF + d];
    }
#pragma unroll
    for (int off = 32; off > 0; off >>= 1) {
      nrm += __shfl_xor(nrm, off);
      a0 += __shfl_xor(a0, off);
      a1 += __shfl_xor(a1, off);
      a2 += __shfl_xor(a2, off);
      a3 += __shfl_xor(a3, off);
      a4 += __shfl_xor(a4, off);
    }
    if (lane == 0) {
      const float sc = 1.0f / fmaxf(sqrtf(nrm), 1e-12f);
      float* op = out + ((size_t)bb * NQ + q) * 5;
      op[0] = a0 * sc;
      op[1] = a1 * sc;
      op[2] = a2 * sc;
      op[3] = a3 * sc;
      op[4] = a4 * sc;
    }
  }
}

// =====================================================================
extern "C" void kernel_launch(void* const* d_in, const int* in_sizes, int n_in,
                              void* d_out, int out_size, void* d_ws,
                              size_t ws_size, hipStream_t stream) {
  const float* ftest = (const float*)d_in[0];
  const float* ftrain = (const float*)d_in[1];
  const int* usimple = (const int*)d_in[4];
  float* out = (float*)d_out;
  const int B = in_sizes[1] / (NSUP * DF);

  fused_kernel<<<dim3(B), dim3(TPB), 0, stream>>>(ftrain, ftest, usimple,
                                                  out);
}

// Round 2
// 478.633 us; speedup vs baseline: 1.3139x; 1.3139x over previous
//
#include <hip/hip_runtime.h>
#include <math.h>

#define NWAY 5
#define NSUP 25
#define NZV  125
#define DF   640
#define NQ   75
#define TPB  640   // two batches per block: waves 0-4 batch A, 5-9 batch B

// =====================================================================
// Fast transform: tf(x) = sign(x) * (g(|x|+1e-5) - g(1e-5)),
//   g(t) = ln(1/t+1)^{-1.3} = exp2(-1.3*log2(log2(1/t+1)) + A),
//   A = -1.3*log2(ln2) = 0.68739628. 4 transcendentals vs reference's 8.
// =====================================================================
__device__ __forceinline__ float gfun(float t) {
  const float l2 = __log2f(__builtin_amdgcn_rcpf(t) + 1.0f);
  return __builtin_amdgcn_exp2f(fmaf(-1.3f, __log2f(l2), 0.68739628f));
}
__device__ __forceinline__ float simple_tf(float x, float Cg) {
  const float s = gfun(fabsf(x) + 1e-5f) - Cg;
  return (x >= 0.0f) ? s : -s;
}

// Fast fp64 reciprocal: v_rcp_f64 (+~2^-27 rel err) + 2 Newton steps ->
// full fp64 accuracy; ~half the latency of the compiler's exact divide.
// Inputs here are strictly-positive pivots / s / z values (no inf/nan).
__device__ __forceinline__ double fdrcp(double d) {
  double r;
  asm("v_rcp_f64 %0, %1" : "=v"(r) : "v"(d));
  r = r * fma(-d, r, 2.0);
  r = r * fma(-d, r, 2.0);
  return r;
}

// Constant-lane fp64 broadcast via v_readlane (VALU, off the LDS pipe).
__device__ __forceinline__ double bcastd(double v, const int srclane) {
  const int lo = __builtin_amdgcn_readlane(__double2loint(v), srclane);
  const int hi = __builtin_amdgcn_readlane(__double2hiint(v), srclane);
  return __hiloint2double(hi, lo);
}

// In-place Gauss-Jordan of 25x25 SPD; columns live on lanes BASE..BASE+24.
template <int BASE, int J>
__device__ __forceinline__ void gjp(double (&a)[25], const int lane,
                                    const bool act) {
  const double djj = bcastd(a[J], BASE + J);
  const double pinv = fdrcp(djj);
  if (act) a[J] = ((lane == BASE + J) ? 1.0 : a[J]) * pinv;
#pragma unroll
  for (int r = 0; r < 25; ++r) {
    if (r != J) {
      const double f = bcastd(a[r], BASE + J);
      if (act) a[r] = ((lane == BASE + J) ? 0.0 : a[r]) - f * a[J];
    }
  }
}
template <int BASE, int J = 0>
__device__ __forceinline__ void gjall(double (&a)[25], const int lane,
                                      const bool act) {
  if constexpr (J < 25) {
    gjp<BASE, J>(a, lane, act);
    gjall<BASE, J + 1>(a, lane, act);
  }
}

// Factorize (per half): hv <- row `lane` of Hinv_w; this half's wave-0
// lanes 32-56 additionally get Winv = (sum_k Hinv_k)^-1 rows.
// W accumulation uses native LDS fp64 atomics (ds_add_f64): 2 barriers
// instead of the old 1+5 sequential-wave scheme.
__device__ __forceinline__ void factorize(const double* Msh, const double* dd,
                                          double* W, double (&hv)[25],
                                          const int tl, const int lane,
                                          const int w) {
  if (lane < 25) {
#pragma unroll
    for (int j = 0; j < 25; ++j)
      hv[j] = Msh[lane * 26 + j] + ((j == lane) ? dd[lane * 5 + w] : 0.0);
  }
  gjall<0>(hv, lane, true);
  for (int i2 = tl; i2 < 650; i2 += 320) W[i2] = 0.0;
  __syncthreads();
  if (lane < 25) {
#pragma unroll
    for (int j = 0; j < 25; ++j)
      __hip_atomic_fetch_add(&W[lane * 26 + j], hv[j], __ATOMIC_RELAXED,
                             __HIP_MEMORY_SCOPE_WORKGROUP);
  }
  __syncthreads();
  if (w == 0) {
    if (lane >= 32 && lane < 57) {
#pragma unroll
      for (int r = 0; r < 25; ++r) hv[r] = W[(lane - 32) * 26 + r];
    }
    gjall<32>(hv, lane, lane >= 32 && lane < 57);
  }
  // next consumer phase begins with its own __syncthreads()
}

// KKT solve (per half). ZRS: rs==0; ZR: rx=rz=ry==0; ACC: accumulate.
// di = 1/dd precomputed -> the two per-solve divides become multiplies.
template <bool ZRS, bool ZR, bool ACC>
__device__ __forceinline__ void kkt_solve(
    const double* Msh, const double* dd, const double* di, double* tt,
    double* c1, double* c2, double* vv, double* gg, double* dyw,
    const double* rx, const double* rs, const double* rz, const double* ry,
    double (&hv)[25], double* dx, double* ds, double* dz, double* dy,
    const int tl, const int lane, const int w) {
  if (tl < NZV) {
    double t = ZR ? 0.0 : rz[tl];
    if (!ZRS) t -= rs[tl] * di[tl];
    tt[tl] = t;
  }
  __syncthreads();
  if (tl < NZV) {
    const int i = tl / 5, k = tl - i * 5;
    double acc = ZR ? 0.0 : -rx[tl];
#pragma unroll
    for (int j = 0; j < 25; ++j) acc += Msh[i * 26 + j] * tt[j * 5 + k];
    c1[tl] = acc;
  } else if (tl >= 128 && tl < 153) {
    const int i = tl - 128;
    double acc = ZR ? 0.0 : -ry[i];
#pragma unroll
    for (int k = 0; k < 5; ++k) acc += tt[i * 5 + k];
    c2[i] = acc;
  }
  __syncthreads();
  if (lane < 25) {
    double acc = 0.0;
#pragma unroll
    for (int j = 0; j < 25; ++j) acc += hv[j] * c1[j * 5 + w];
    vv[lane * 5 + w] = acc;
  }
  __syncthreads();
  if (w == 0) {  // gg then dy in the SAME wave: LDS program order suffices
    if (lane < 25) {
      double acc = -c2[lane];
#pragma unroll
      for (int k = 0; k < 5; ++k) acc += vv[lane * 5 + k];
      gg[lane] = acc;
    }
    if (lane >= 32 && lane < 57) {
      double acc = 0.0;
#pragma unroll
      for (int r = 0; r < 25; ++r) acc += hv[r] * gg[r];
      dyw[lane - 32] = acc;
      if (ACC) dy[lane - 32] += acc; else dy[lane - 32] = acc;
    }
  }
  __syncthreads();
  if (lane < 25) {
    double acc = 0.0;
#pragma unroll
    for (int j = 0; j < 25; ++j) acc += hv[j] * dyw[j];
    const int v = lane * 5 + w;
    const double u = vv[v] - acc;
    const double dzv = dd[v] * u;
    const double dxv = u - tt[v];
    const double dsv = ((ZRS ? 0.0 : -rs[v]) - dzv) * di[v];
    if (ACC) { dz[v] += dzv; dx[v] += dxv; ds[v] += dsv; }
    else     { dz[v]  = dzv; dx[v]  = dxv; ds[v]  = dsv; }
  }
  __syncthreads();
}

// Per-half block reduction: first wave of the half reduces buf[0..n).
__device__ __forceinline__ double bred(const double* buf, int n, int ismin,
                                       double* SCh, const int w,
                                       const int lane) {
  __syncthreads();
  if (w == 0) {
    double acc = ismin ? 1e300 : 0.0;
    for (int m = lane; m < n; m += 64) {
      const double v = buf[m];
      acc = ismin ? fmin(acc, v) : (acc + v);
    }
#pragma unroll
    for (int off = 32; off > 0; off >>= 1) {
      const double o = __shfl_xor(acc, off);
      acc = ismin ? fmin(acc, o) : (acc + o);
    }
    if (lane == 0) SCh[15] = acc;
  }
  __syncthreads();
  return SCh[15];
}

// stage 64 columns of RAW transformed train rows into GBUF[25][68].
// (Normalization is folded into M-scaling / bxs instead.)
__device__ __forceinline__ void stage_chunk(const float* __restrict__ tb,
                                            const int ch, const bool us,
                                            const float Cg, float* GBUF,
                                            const int tl) {
  for (int idx = tl; idx < 1600; idx += 320) {
    const int r = idx >> 6, cc = idx & 63;
    float v = tb[r * DF + (ch << 6) + cc];
    if (us) v = simple_tf(v, Cg);
    GBUF[r * 68 + cc] = v;
  }
}

// =====================================================================
// fused_kernel: TWO batches per 640-thread block (waves 0-4 / 5-9),
// grid B/2 = 256 -> 1 block/CU, 10 waves resident (the proven-fast
// occupancy shape; 320-thread blocks do NOT co-schedule 2/CU).
// The old out_kernel is fused as phase 5; its xfs buffer overlays the
// dead QP arrays (Msh..tt region) via a flat per-half LDS pool.
// Row norms are derived from the raw Gram diagonal (old phase 1 gone).
// =====================================================================
__global__ void __launch_bounds__(TPB, 2) fused_kernel(
    const float* __restrict__ train, const float* __restrict__ test,
    const int* __restrict__ usimple, float* __restrict__ out, const int B) {
  const int tid = threadIdx.x;
  const int half = tid >= 320 ? 1 : 0;
  const int tl = tid - 320 * half;
  const int lane = tid & 63;
  const int w = tl >> 6;
  const int bb = 2 * blockIdx.x + half;
  const bool live = bb < B;
  const bool us = (usimple[0] != 0);
  const float Cg = gfun(1e-5f);

  // Flat per-half LDS pool (offsets in doubles). 2*3496*8 = 55936 B.
  __shared__ __align__(16) double POOL[2][3496];
  double* ph = POOL[half];
  double* Msh = ph + 0;      // 650
  double* x   = ph + 650;    // 125
  double* sv  = ph + 775;    // 125
  double* zv  = ph + 900;    // 125
  double* rx  = ph + 1025;   // 125
  double* rz  = ph + 1150;   // 125
  double* dd  = ph + 1275;   // 125
  double* di  = ph + 1400;   // 125 (1/dd)
  double* tt  = ph + 1525;   // 125
  double* c1  = ph + 1650;   // 125
  double* vv  = ph + 1775;   // 125
  double* dxa = ph + 1900;   // 125
  double* dsa = ph + 2025;   // 125
  double* dza = ph + 2150;   // 125
  double* rsc = ph + 2275;   // 125
  double* yv  = ph + 2400;   // 25
  double* ry  = ph + 2425;   // 25
  double* c2  = ph + 2450;   // 25 (also dinvn before the QP starts)
  double* gg  = ph + 2475;   // 25
  double* dya = ph + 2500;   // 25
  double* dyw = ph + 2525;   // 25
  double* SC  = ph + 2550;   // 16
  float*  invn = (float*)(ph + 2566);  // 25 floats
  float*  bxs  = (float*)(ph + 2579);  // 125 floats
  double* W    = ph + 2644;            // 850 doubles = 6800 B (16B-aligned)
  float*  GBUF = (float*)(ph + 2644);
  float*  xfs  = (float*)ph;  // phases 4-5 ONLY: overlays Msh..tt (dead)
  double* dinvn = c2;

  double hv[25];

  const float* tb = train + (size_t)(live ? bb : 0) * NSUP * DF;

  // ---- phase 2: chunked RAW Gram G = F F^T (fp64 accumulate) ----
  int i1, j1, i2v = 0, j2v = 0;
  {
    int rem = tl, i = 0;
    while (rem >= NSUP - i) { rem -= NSUP - i; ++i; }
    i1 = i; j1 = i + rem;
  }
  if (tl < 5) {
    int rem = 320 + tl, i = 0;
    while (rem >= NSUP - i) { rem -= NSUP - i; ++i; }
    i2v = i; j2v = i + rem;
  }
  double acc1 = 0.0, acc2 = 0.0;
  for (int ch = 0; ch < 10; ++ch) {
    stage_chunk(tb, ch, us, Cg, GBUF, tl);
    __syncthreads();
    {
      const float4* ra = (const float4*)(GBUF + i1 * 68);
      const float4* rb = (const float4*)(GBUF + j1 * 68);
#pragma unroll
      for (int c = 0; c < 16; ++c) {
        float4 av = ra[c], bv = rb[c];
        acc1 += (double)av.x * bv.x + (double)av.y * bv.y +
                (double)av.z * bv.z + (double)av.w * bv.w;
      }
    }
    if (tl < 5) {
      const float4* ra = (const float4*)(GBUF + i2v * 68);
      const float4* rb = (const float4*)(GBUF + j2v * 68);
#pragma unroll
      for (int c = 0; c < 16; ++c) {
        float4 av = ra[c], bv = rb[c];
        acc2 += (double)av.x * bv.x + (double)av.y * bv.y +
                (double)av.z * bv.z + (double)av.w * bv.w;
      }
    }
    __syncthreads();
  }
  Msh[i1 * 26 + j1] = acc1;
  if (i1 != j1) Msh[j1 * 26 + i1] = acc1;
  if (tl < 5) {
    Msh[i2v * 26 + j2v] = acc2;
    if (i2v != j2v) Msh[j2v * 26 + i2v] = acc2;
  }
  __syncthreads();

  // ---- norms from Gram diagonal; then scale M = D G D + I ----
  if (tl < 25) {
    const double g = Msh[tl * 27];
    const double dn = 1.0 / fmax(sqrt(g), 1e-12);
    dinvn[tl] = dn;
    invn[tl] = (float)dn;
  }
  __syncthreads();
  for (int idx = tl; idx < 650; idx += 320) {
    const int i = idx / 26, j = idx - i * 26;
    if (j < 25) {
      double v = Msh[idx] * dinvn[i] * dinvn[j];
      if (i == j) v += 1.0;
      Msh[idx] = v;
    }
  }

  // ---- phase 3: QP init ----
  if (tl < NZV) {
    const int i = tl / 5, k = tl - i * 5;
    const double oh = (k == (i % 5)) ? 1.0 : 0.0;
    rx[tl] = -oh;
    rz[tl] = -0.1 * oh;
    dd[tl] = 1.0;
    di[tl] = 1.0;
  } else if (tl >= 128 && tl < 153) {
    ry[tl - 128] = 0.0;
  }
  if (tl == 0) SC[0] = 1e300;
  __syncthreads();

  factorize(Msh, dd, W, hv, tl, lane, w);
  kkt_solve<true, false, false>(Msh, dd, di, tt, c1, c2, vv, gg, dyw, rx,
                                (const double*)nullptr, rz, ry, hv, x, sv, zv,
                                yv, tl, lane, w);
  {
    const double ms = bred(sv, NZV, 1, SC, w, lane);
    if (ms < 0.0 && tl < NZV) sv[tl] -= (ms - 1.0);
    const double mz = bred(zv, NZV, 1, SC, w, lane);
    if (mz < 0.0 && tl < NZV) zv[tl] -= (mz - 1.0);
  }
  if (tl < NZV) bxs[tl] = (float)x[tl];

#pragma unroll 1
  for (int it = 0; it < 3; ++it) {
    __syncthreads();
    if (tl < NZV) {
      const int i = tl / 5, k = tl - i * 5;
      double acc = 0.0;
#pragma unroll
      for (int j = 0; j < 25; ++j) acc += Msh[i * 26 + j] * x[j * 5 + k];
      const double oh = (k == (i % 5)) ? 1.0 : 0.0;
      rx[tl] = yv[i] + zv[tl] + acc - oh;
      rz[tl] = x[tl] + sv[tl] - 0.1 * oh;
    } else if (tl >= 128 && tl < 153) {
      const int i = tl - 128;
      double acc = 0.0;
#pragma unroll
      for (int k = 0; k < 5; ++k) acc += x[i * 5 + k];
      ry[i] = acc;
    }
    __syncthreads();
    if (w == 0) {  // per-half consolidated 4-sum reduction (first wave)
      double s1 = 0, s2 = 0, s3 = 0, s4 = 0;
      for (int m = lane; m < 125; m += 64) {
        s1 += sv[m] * zv[m];
        s2 += rx[m] * rx[m];
        s3 += rz[m] * rz[m];
      }
      if (lane < 25) s4 = ry[lane] * ry[lane];
#pragma unroll
      for (int off = 32; off > 0; off >>= 1) {
        s1 += __shfl_xor(s1, off);
        s2 += __shfl_xor(s2, off);
        s3 += __shfl_xor(s3, off);
        s4 += __shfl_xor(s4, off);
      }
      if (lane == 0) { SC[2] = s1; SC[3] = s2; SC[4] = s3; SC[5] = s4; }
    }
    __syncthreads();
    const double szsum = SC[2];
    const double mu = fabs(szsum) / 125.0;
    const double res = sqrt(SC[4] + 1e-30) + sqrt(SC[5] + 1e-30) +
                       sqrt(SC[3] + 1e-30) + 125.0 * mu;
    if (tl == 0) {
      if (res < SC[0]) { SC[0] = res; SC[1] = 1.0; } else SC[1] = 0.0;
    }
    __syncthreads();
    if (SC[1] != 0.0 && tl < NZV) bxs[tl] = (float)x[tl];
    if (it == 2) break;
    __syncthreads();

    if (tl < NZV) {
      const double rs_ = fdrcp(sv[tl]);
      const double rz_ = fdrcp(zv[tl]);
      dd[tl] = zv[tl] * rs_;
      di[tl] = sv[tl] * rz_;
    }
    __syncthreads();
    factorize(Msh, dd, W, hv, tl, lane, w);
    kkt_solve<false, false, false>(Msh, dd, di, tt, c1, c2, vv, gg, dyw, rx,
                                   zv, rz, ry, hv, dxa, dsa, dza, dya, tl,
                                   lane, w);
    if (tl < NZV) {
      const double a1 = (dza[tl] < 0.0) ? (-zv[tl] / dza[tl]) : 1e12;
      const double a2 = (dsa[tl] < 0.0) ? (-sv[tl] / dsa[tl]) : 1e12;
      tt[tl] = fmin(a1, a2);
    }
    const double aff = fmin(bred(tt, NZV, 1, SC, w, lane), 1.0);
    if (tl < NZV)
      tt[tl] = (sv[tl] + aff * dsa[tl]) * (zv[tl] + aff * dza[tl]);
    const double num = bred(tt, NZV, 0, SC, w, lane);
    const double sg = num / szsum;
    const double musig = mu * (sg * sg * sg);
    if (tl < NZV) rsc[tl] = (-musig + dsa[tl] * dza[tl]) * fdrcp(sv[tl]);
    __syncthreads();
    kkt_solve<false, true, true>(Msh, dd, di, tt, c1, c2, vv, gg, dyw, rx,
                                 rsc, rz, ry, hv, dxa, dsa, dza, dya, tl,
                                 lane, w);
    if (tl < NZV) {
      const double a1 = (dza[tl] < 0.0) ? (-zv[tl] / dza[tl]) : 1e12;
      const double a2 = (dsa[tl] < 0.0) ? (-sv[tl] / dsa[tl]) : 1e12;
      tt[tl] = fmin(a1, a2);
    }
    const double al = fmin(0.999 * bred(tt, NZV, 1, SC, w, lane), 1.0);
    if (tl < NZV) {
      x[tl] += al * dxa[tl];
      sv[tl] += al * dsa[tl];
      zv[tl] += al * dza[tl];
    } else if (tl >= 128 && tl < 153) {
      const int i = tl - 128;
      yv[i] += al * dya[i];
    }
  }
  __syncthreads();

  // ---- phase 4: xfs[w][d] = sum_s (bx[s,w]*invn[s]) * Fraw[s][d] ----
  // xfs overlays the dead Msh..tt region; all QP state reads are done.
  float xs[25];
#pragma unroll
  for (int s_ = 0; s_ < 25; ++s_) xs[s_] = bxs[s_ * 5 + w] * invn[s_];
  for (int ch = 0; ch < 10; ++ch) {
    stage_chunk(tb, ch, us, Cg, GBUF, tl);
    __syncthreads();
    float acc = 0.0f;
#pragma unroll
    for (int s_ = 0; s_ < 25; ++s_) acc += xs[s_] * GBUF[s_ * 68 + lane];
    xfs[w * DF + (ch << 6) + lane] = acc;
    __syncthreads();
  }
  // trailing __syncthreads above makes all xfs writes visible

  // ---- phase 5: query dot products (old out_kernel, fused) ----
  // wave w handles queries w, w+5, ..., w+70 (15 each); unroll 2 keeps
  // two queries' global loads in flight.
  const float* qb = test + (size_t)(live ? bb : 0) * NQ * DF;
#pragma unroll 2
  for (int jj = 0; jj < 15; ++jj) {
    const int q = w + 5 * jj;
    const float* qr = qb + (size_t)q * DF;
    float nrm = 0.0f, a0 = 0.0f, a1 = 0.0f, a2 = 0.0f, a3 = 0.0f, a4 = 0.0f;
#pragma unroll
    for (int c = 0; c < 10; ++c) {
      const int d = lane + 64 * c;
      float v = qr[d];
      if (us) v = simple_tf(v, Cg);
      nrm += v * v;
      a0 += v * xfs[0 * DF + d];
      a1 += v * xfs[1 * DF + d];
      a2 += v * xfs[2 * DF + d];
      a3 += v * xfs[3 * DF + d];
      a4 += v * xfs[4 * DF + d];
    }
#pragma unroll
    for (int off = 32; off > 0; off >>= 1) {
      nrm += __shfl_xor(nrm, off);
      a0 += __shfl_xor(a0, off);
      a1 += __shfl_xor(a1, off);
      a2 += __shfl_xor(a2, off);
      a3 += __shfl_xor(a3, off);
      a4 += __shfl_xor(a4, off);
    }
    if (live && lane == 0) {
      const float sc = 1.0f / fmaxf(sqrtf(nrm), 1e-12f);
      float* op = out + ((size_t)bb * NQ + q) * 5;
      op[0] = a0 * sc;
      op[1] = a1 * sc;
      op[2] = a2 * sc;
      op[3] = a3 * sc;
      op[4] = a4 * sc;
    }
  }
}

// =====================================================================
extern "C" void kernel_launch(void* const* d_in, const int* in_sizes, int n_in,
                              void* d_out, int out_size, void* d_ws,
                              size_t ws_size, hipStream_t stream) {
  const float* ftest = (const float*)d_in[0];
  const float* ftrain = (const float*)d_in[1];
  const int* usimple = (const int*)d_in[4];
  float* out = (float*)d_out;
  const int B = in_sizes[1] / (NSUP * DF);

  fused_kernel<<<dim3((B + 1) / 2), dim3(TPB), 0, stream>>>(ftrain, ftest,
                                                            usimple, out, B);
}